// Round 7
// baseline (220.809 us; speedup 1.0000x reference)
//
#include <hip/hip_runtime.h>
#include <hip/hip_fp16.h>

// SuppLayer: out[b,c] = exp( sum_s x[b, cm[c,s]] * w[c,s] )
// B=4096, NCLASS=1000, NSUPP=64, NCHUNK=4096.
//
// R16: overlap schedule REDESIGNED TO FIT THE 64-VGPR CAP.
//  Evidence: 1024-thr blocks get a hard 64-VGPR budget on gfx950
//  ((1024,4) and (1024,1) both -> VGPR_Count=64, identical spills).
//  R13-R15's 64-reg resident cm/w cannot coexist with streaming regs.
//  Design: depth-4 rotating cm/w slot buffer (4 sg groups = 32 VGPR).
//  Fully unrolled 16 passes: pass i gathers sg_i from slot (i&3)
//  (VMEM-free), then refills that slot with sg_{i+4}. Hi-row staging =
//  4 one-column chunks (8 VGPR), issued at pass 0/4/8/12, cvt'd 4 passes
//  later (~1.6us flight >= 1.33us stream need). vmcnt safety by
//  CONSTRUCTION: anything a pass waits on (slot refill from 4 passes ago)
//  is OLDER than the in-flight chunk, so counted waits never drain the
//  stream; a chunk's drain coincides with its cvt. sched_barrier(0) pins
//  section order. Live set ~60 <= 64: acc 8 + slots 32 + chunk 8 + addr.
//  Tail threads (t>=1000) clamp c=999 (no divergence; stores guarded).
//  Phase 2 (hi gather) reuses the rotation with no chunks.
//  Slot = 16 B = 8 rows fp16; read quad = idx&7; pre-pass counting-sorts
//  by (idx-c)&7 so a wave's 64 consecutive classes cycle all 8 quads.

constexpr int B_       = 4096;
constexpr int NCLASS_  = 1000;
constexpr int NSUPP_   = 64;
constexpr int NCHUNK_  = 4096;
constexpr int BT       = 16;     // batch rows per block
constexpr int BH       = BT / 2; // rows per half-tile
constexpr int THREADS_ = 1024;
constexpr int SG_      = NSUPP_ / 4;            // 16 int4/float4 groups
constexpr size_t CMT_BYTES = (size_t)SG_ * NCLASS_ * 16;   // 256 KB
constexpr size_t WS_NEEDED = 2 * CMT_BYTES;                // 512 KB

// ---- pre-pass: one wave per class. Sort 64 (idx,w) by key=(idx-c)&7 and
// write to [sg][class] transposed layout. All-register rank computation. ----
__global__ __launch_bounds__(256)
void build_cw_kernel(const int*   __restrict__ cm,
                     const float* __restrict__ w,
                     int*         __restrict__ cmT,
                     float*       __restrict__ wT)
{
    const int t    = threadIdx.x;
    const int c    = blockIdx.x * 4 + (t >> 6);   // 4 classes per block
    const int lane = t & 63;
    if (c >= NCLASS_) return;                      // grid=250 -> never taken

    const int   idx = cm[c * NSUPP_ + lane];
    const float wv  = w [c * NSUPP_ + lane];
    const int   key = (idx - c) & 7;               // read quad = idx&7

    const unsigned long long below = ((unsigned long long)1 << lane) - 1ull;
    int j = 0;
    #pragma unroll
    for (int r = 0; r < 8; ++r) {
        const unsigned long long m = __ballot(key == r);
        if (key > r)  j += __popcll(m);
        if (key == r) j += __popcll(m & below);
    }

    const int dst = ((j >> 2) * NCLASS_ + c) * 4 + (j & 3);
    cmT[dst] = idx;
    wT [dst] = wv;
}

// fp16x2 (packed) <-> float bit-cast helpers, no address-of-local
static __device__ __forceinline__ float2 hx2f(const float u) {
    union U { float f; __half2 h; } uu;
    uu.f = u;
    return __half22float2(uu.h);
}
static __device__ __forceinline__ float h2f(const __half2 h) {
    union U { __half2 h; float f; } uu;
    uu.h = h;
    return uu.f;
}

#define SB() __builtin_amdgcn_sched_barrier(0)

// one packed half2 lane-pair: 2 fma into acc pair A
#define SUPP_FMA(dc, wc, A) {                          \
    const float2 f_ = hx2f(dc);                        \
    (A).x = fmaf(f_.x, (wc), (A).x);                   \
    (A).y = fmaf(f_.y, (wc), (A).y); }

#define GONE(d, wc)                                    \
    SUPP_FMA((d).x, (wc), a0)                          \
    SUPP_FMA((d).y, (wc), a1)                          \
    SUPP_FMA((d).z, (wc), a2)                          \
    SUPP_FMA((d).w, (wc), a3)

// gather one sg group from slot J at tile base T4: 4 ds_read_b128 + 32 fma
#define GATHER(J, T4) {                                \
    const float4 d0_ = (T4)[cwS##J.x];                 \
    const float4 d1_ = (T4)[cwS##J.y];                 \
    const float4 d2_ = (T4)[cwS##J.z];                 \
    const float4 d3_ = (T4)[cwS##J.w];                 \
    GONE(d0_, wvS##J.x)                                \
    GONE(d1_, wvS##J.y)                                \
    GONE(d2_, wvS##J.z)                                \
    GONE(d3_, wvS##J.w) }

// refill slot J with sg group S (2 VMEM loads)
#define REFILL(J, S)                                                         \
    if constexpr (USET) {                                                    \
        cwS##J = cmT[(S) * NCLASS_ + c];                                     \
        wvS##J = wT [(S) * NCLASS_ + c];                                     \
    } else {                                                                 \
        cwS##J = reinterpret_cast<const int4*>(cmap + c * NSUPP_)[(S)];      \
        wvS##J = reinterpret_cast<const float4*>(wSupp + c * NSUPP_)[(S)];   \
    }

// issue one hi-row column chunk (8 loads) into hv0..7
#define CHUNK_ISSUE(Q) {                                                     \
    const size_t colq_ = (size_t)t + THREADS_ * (Q);                         \
    hv0 = x[(size_t)(rb +  8) * NCHUNK_ + colq_];                            \
    hv1 = x[(size_t)(rb +  9) * NCHUNK_ + colq_];                            \
    hv2 = x[(size_t)(rb + 10) * NCHUNK_ + colq_];                            \
    hv3 = x[(size_t)(rb + 11) * NCHUNK_ + colq_];                            \
    hv4 = x[(size_t)(rb + 12) * NCHUNK_ + colq_];                            \
    hv5 = x[(size_t)(rb + 13) * NCHUNK_ + colq_];                            \
    hv6 = x[(size_t)(rb + 14) * NCHUNK_ + colq_];                            \
    hv7 = x[(size_t)(rb + 15) * NCHUNK_ + colq_]; }

// convert chunk Q and write its thi slot (one b128)
#define CHUNK_CVT(Q) {                                                       \
    const size_t colq_ = (size_t)t + THREADS_ * (Q);                         \
    float4 pk_;                                                              \
    pk_.x = h2f(__floats2half2_rn(hv0, hv1));                                \
    pk_.y = h2f(__floats2half2_rn(hv2, hv3));                                \
    pk_.z = h2f(__floats2half2_rn(hv4, hv5));                                \
    pk_.w = h2f(__floats2half2_rn(hv6, hv7));                                \
    *reinterpret_cast<float4*>(&thi[colq_ * 4]) = pk_; }

template <bool USET>
__global__ __launch_bounds__(THREADS_)
void supp_gather_kernel(const float* __restrict__ x,
                        const float* __restrict__ wSupp,
                        const int*   __restrict__ cmap,
                        const float4* __restrict__ wT,
                        const int4*   __restrict__ cmT,
                        float*       __restrict__ out)
{
    // two 64 KB halves; slot idx = 16 B = 8 rows as half2 pairs
    __shared__ __align__(16) __half2 tile[NCHUNK_ * 8];
    __half2* tlo = tile;
    __half2* thi = tile + NCHUNK_ * 4;
    const float4* tlo4 = reinterpret_cast<const float4*>(tlo);
    const float4* thi4 = reinterpret_cast<const float4*>(thi);

    const int t  = threadIdx.x;
    const int rb = blockIdx.x * BT;   // first batch row of this tile
    const int c  = (t < NCLASS_) ? t : NCLASS_ - 1;   // clamp tail, no branch

    // ---- rotating cm/w slots (4 sg groups = 32 VGPR) ----
    int4   cwS0, cwS1, cwS2, cwS3;
    float4 wvS0, wvS1, wvS2, wvS3;
    REFILL(0, 0) REFILL(1, 1) REFILL(2, 2) REFILL(3, 3)

    // ---- stage rows rb..rb+7 -> fp16 -> tlo ----
    #pragma unroll
    for (int p = 0; p < NCHUNK_ / THREADS_; ++p) {
        const size_t col = (size_t)t + THREADS_ * p;
        float v0 = x[(size_t)(rb + 0) * NCHUNK_ + col];
        float v1 = x[(size_t)(rb + 1) * NCHUNK_ + col];
        float v2 = x[(size_t)(rb + 2) * NCHUNK_ + col];
        float v3 = x[(size_t)(rb + 3) * NCHUNK_ + col];
        float v4 = x[(size_t)(rb + 4) * NCHUNK_ + col];
        float v5 = x[(size_t)(rb + 5) * NCHUNK_ + col];
        float v6 = x[(size_t)(rb + 6) * NCHUNK_ + col];
        float v7 = x[(size_t)(rb + 7) * NCHUNK_ + col];
        float4 pk;
        pk.x = h2f(__floats2half2_rn(v0, v1));
        pk.y = h2f(__floats2half2_rn(v2, v3));
        pk.z = h2f(__floats2half2_rn(v4, v5));
        pk.w = h2f(__floats2half2_rn(v6, v7));
        *reinterpret_cast<float4*>(&tlo[col * 4]) = pk;
    }
    __syncthreads();

    float2 a0 = {0.f, 0.f}, a1 = {0.f, 0.f}, a2 = {0.f, 0.f}, a3 = {0.f, 0.f};
    float hv0, hv1, hv2, hv3, hv4, hv5, hv6, hv7;

    // ---- overlap loop: lo gather (16 sg) || hi stream (4 chunks) ----
    CHUNK_ISSUE(0) SB();
    /*  0 */ GATHER(0, tlo4) SB(); REFILL(0,  4) SB();
    /*  1 */ GATHER(1, tlo4) SB(); REFILL(1,  5) SB();
    /*  2 */ GATHER(2, tlo4) SB(); REFILL(2,  6) SB();
    /*  3 */ GATHER(3, tlo4) SB(); REFILL(3,  7) SB();
    /*  4 */ CHUNK_CVT(0) CHUNK_ISSUE(1) SB();
             GATHER(0, tlo4) SB(); REFILL(0,  8) SB();
    /*  5 */ GATHER(1, tlo4) SB(); REFILL(1,  9) SB();
    /*  6 */ GATHER(2, tlo4) SB(); REFILL(2, 10) SB();
    /*  7 */ GATHER(3, tlo4) SB(); REFILL(3, 11) SB();
    /*  8 */ CHUNK_CVT(1) CHUNK_ISSUE(2) SB();
             GATHER(0, tlo4) SB(); REFILL(0, 12) SB();
    /*  9 */ GATHER(1, tlo4) SB(); REFILL(1, 13) SB();
    /* 10 */ GATHER(2, tlo4) SB(); REFILL(2, 14) SB();
    /* 11 */ GATHER(3, tlo4) SB(); REFILL(3, 15) SB();
    /* 12 */ CHUNK_CVT(2) CHUNK_ISSUE(3) SB();
             GATHER(0, tlo4) SB();
    /* 13 */ GATHER(1, tlo4) SB();
    /* 14 */ GATHER(2, tlo4) SB();
    /* 15 */ GATHER(3, tlo4) SB();
    CHUNK_CVT(3) SB();

    // ---- lo rows complete: exp + store (overlaps barrier wait) ----
    if (t < NCLASS_) {
        out[(size_t)(rb + 0) * NCLASS_ + c] = __expf(a0.x);
        out[(size_t)(rb + 1) * NCLASS_ + c] = __expf(a0.y);
        out[(size_t)(rb + 2) * NCLASS_ + c] = __expf(a1.x);
        out[(size_t)(rb + 3) * NCLASS_ + c] = __expf(a1.y);
        out[(size_t)(rb + 4) * NCLASS_ + c] = __expf(a2.x);
        out[(size_t)(rb + 5) * NCLASS_ + c] = __expf(a2.y);
        out[(size_t)(rb + 6) * NCLASS_ + c] = __expf(a3.x);
        out[(size_t)(rb + 7) * NCLASS_ + c] = __expf(a3.y);
    }
    // re-prime slots for the hi phase (drained harmlessly at the barrier)
    REFILL(0, 0) REFILL(1, 1) REFILL(2, 2) REFILL(3, 3)
    __syncthreads();

    // ---- hi gather: 16 sg over thi, same rotation, no streaming ----
    a0 = {0.f, 0.f}; a1 = {0.f, 0.f}; a2 = {0.f, 0.f}; a3 = {0.f, 0.f};
    GATHER(0, thi4) REFILL(0,  4)
    GATHER(1, thi4) REFILL(1,  5)
    GATHER(2, thi4) REFILL(2,  6)
    GATHER(3, thi4) REFILL(3,  7)
    GATHER(0, thi4) REFILL(0,  8)
    GATHER(1, thi4) REFILL(1,  9)
    GATHER(2, thi4) REFILL(2, 10)
    GATHER(3, thi4) REFILL(3, 11)
    GATHER(0, thi4) REFILL(0, 12)
    GATHER(1, thi4) REFILL(1, 13)
    GATHER(2, thi4) REFILL(2, 14)
    GATHER(3, thi4) REFILL(3, 15)
    GATHER(0, thi4)
    GATHER(1, thi4)
    GATHER(2, thi4)
    GATHER(3, thi4)

    if (t < NCLASS_) {
        out[(size_t)(rb +  8) * NCLASS_ + c] = __expf(a0.x);
        out[(size_t)(rb +  9) * NCLASS_ + c] = __expf(a0.y);
        out[(size_t)(rb + 10) * NCLASS_ + c] = __expf(a1.x);
        out[(size_t)(rb + 11) * NCLASS_ + c] = __expf(a1.y);
        out[(size_t)(rb + 12) * NCLASS_ + c] = __expf(a2.x);
        out[(size_t)(rb + 13) * NCLASS_ + c] = __expf(a2.y);
        out[(size_t)(rb + 14) * NCLASS_ + c] = __expf(a3.x);
        out[(size_t)(rb + 15) * NCLASS_ + c] = __expf(a3.y);
    }
}

extern "C" void kernel_launch(void* const* d_in, const int* in_sizes, int n_in,
                              void* d_out, int out_size, void* d_ws, size_t ws_size,
                              hipStream_t stream) {
    const float* x  = (const float*)d_in[0];   // (B, NCHUNK) fp32
    const float* w  = (const float*)d_in[1];   // (NCLASS, NSUPP) fp32
    const int*   cm = (const int*)d_in[2];     // (NCLASS, NSUPP) int32
    float*       o  = (float*)d_out;           // (B, NCLASS) fp32

    int*   cmT = (int*)d_ws;
    float* wT  = (float*)((char*)d_ws + CMT_BYTES);

    const dim3 grid(B_ / BT);                  // 256 blocks, 1 per CU
    if (ws_size >= WS_NEEDED) {
        build_cw_kernel<<<dim3((NCLASS_ + 3) / 4), dim3(256), 0, stream>>>(
            cm, w, cmT, wT);
        supp_gather_kernel<true><<<grid, dim3(THREADS_), 0, stream>>>(
            x, w, cm, (const float4*)wT, (const int4*)cmT, o);
    } else {
        supp_gather_kernel<false><<<grid, dim3(THREADS_), 0, stream>>>(
            x, w, cm, (const float4*)wT, (const int4*)cmT, o);
    }
}

// Round 8
// 110.890 us; speedup vs baseline: 1.9912x; 1.9912x over previous
//
#include <hip/hip_runtime.h>
#include <hip/hip_fp16.h>

// SuppLayer: out[b,c] = exp( sum_s x[b, cm[c,s]] * w[c,s] )
// B=4096, NCLASS=1000, NSUPP=64, NCHUNK=4096.
//
// R17: R11's proven-clean structure + packed-fp16 inner math.
//  Session law (R13-R16): 1024-thr blocks get a hard 64-VGPR budget on
//  gfx950; every schedule needing more spills to scratch at ruinous cost
//  (R16: 209 MB scratch writes, 137us gather). So: stay in the envelope.
//  Base = R11 (116.3us-class): BT=8 rows, 512 blocks (2/CU), 64 KB tile,
//  16 B slot = 8 rows fp16, read quad = idx&7, cm/w counting-sorted by
//  (idx-c)&7 into [sg][class] layout.
//  New: v_pk_fma_f16 gather. Weights pre-packed as broadcast half2 in the
//  pre-pass; per support = 4 x __hfma2 (was 8 cvt + 8 fma). fp16 partial
//  sums flushed to f32 every 4 sg groups (16 supports) to bound error:
//  est. feat err ~1% -> absmax ~2e8, threshold 1.6e9 (current headroom
//  24x at 6.7e7). VALU in gather drops ~3x (7us -> ~2.5us per CU).
//  Live set ~52 VGPR: acc 4 (half2) + f32 sums 8 + ci/wh pipe 16 +
//  d-temps 16 + addressing. One-deep cm/w prefetch restored.

constexpr int B_       = 4096;
constexpr int NCLASS_  = 1000;
constexpr int NSUPP_   = 64;
constexpr int NCHUNK_  = 4096;
constexpr int BT       = 8;      // batch rows per block
constexpr int THREADS_ = 1024;
constexpr int SG_      = NSUPP_ / 4;            // 16 int4 groups
constexpr size_t CMT_BYTES = (size_t)SG_ * NCLASS_ * 16;   // 256 KB
constexpr size_t WS_NEEDED = 2 * CMT_BYTES;                // 512 KB

// ---- pre-pass: one wave per class. Sort 64 (idx,w) by key=(idx-c)&7 and
// write to [sg][class] transposed layout. Weights stored as BROADCAST
// half2 pairs (w,w) so the gather needs no in-loop conversion. ----
__global__ __launch_bounds__(256)
void build_cw_kernel(const int*   __restrict__ cm,
                     const float* __restrict__ w,
                     int*         __restrict__ cmT,
                     __half2*     __restrict__ wTh)
{
    const int t    = threadIdx.x;
    const int c    = blockIdx.x * 4 + (t >> 6);   // 4 classes per block
    const int lane = t & 63;
    if (c >= NCLASS_) return;                      // grid=250 -> never taken

    const int   idx = cm[c * NSUPP_ + lane];
    const float wv  = w [c * NSUPP_ + lane];
    const int   key = (idx - c) & 7;               // read quad = idx&7

    // stable rank of this element in sorted-by-key order
    const unsigned long long below = ((unsigned long long)1 << lane) - 1ull;
    int j = 0;
    #pragma unroll
    for (int r = 0; r < 8; ++r) {
        const unsigned long long m = __ballot(key == r);
        if (key > r)  j += __popcll(m);
        if (key == r) j += __popcll(m & below);
    }

    const int dst = ((j >> 2) * NCLASS_ + c) * 4 + (j & 3);
    cmT[dst] = idx;
    wTh[dst] = __float2half2_rn(wv);
}

// float bits <-> packed half2, no address-of-local
static __device__ __forceinline__ __half2 f2h2(const float u) {
    union U { float f; __half2 h; } uu;
    uu.f = u;
    return uu.h;
}
static __device__ __forceinline__ float h2f(const __half2 h) {
    union U { __half2 h; float f; } uu;
    uu.h = h;
    return uu.f;
}

// one support: slot float4 d (8 rows fp16), broadcast half2 weight wj
#define GSUPP(d, wj)                               \
    a0 = __hfma2(f2h2((d).x), (wj), a0);           \
    a1 = __hfma2(f2h2((d).y), (wj), a1);           \
    a2 = __hfma2(f2h2((d).z), (wj), a2);           \
    a3 = __hfma2(f2h2((d).w), (wj), a3);

#define FLUSH_ACC() {                              \
    float2 t_;                                     \
    t_ = __half22float2(a0); f0x += t_.x; f0y += t_.y; \
    t_ = __half22float2(a1); f1x += t_.x; f1y += t_.y; \
    t_ = __half22float2(a2); f2x += t_.x; f2y += t_.y; \
    t_ = __half22float2(a3); f3x += t_.x; f3y += t_.y; \
    a0 = z_; a1 = z_; a2 = z_; a3 = z_; }

template <bool USET>
__global__ __launch_bounds__(THREADS_)
void supp_gather_kernel(const float* __restrict__ x,
                        const float* __restrict__ wSupp,
                        const int*   __restrict__ cmap,
                        const float4* __restrict__ wTh4,
                        const int4*   __restrict__ cmT,
                        float*       __restrict__ out)
{
    // slot idx = 16 B = 8 rows as half2 pairs (rows 2k,2k+1)  -> 64 KB
    __shared__ __align__(16) __half2 tile[NCHUNK_ * 4];

    const int t  = threadIdx.x;
    const int rb = blockIdx.x * BT;   // first batch row of this tile

    // ---- stage: 8 rows of x -> fp16, transposed into LDS ----
    #pragma unroll
    for (int p = 0; p < NCHUNK_ / THREADS_; ++p) {
        const size_t col = (size_t)t + THREADS_ * p;
        float v0 = x[(size_t)(rb + 0) * NCHUNK_ + col];
        float v1 = x[(size_t)(rb + 1) * NCHUNK_ + col];
        float v2 = x[(size_t)(rb + 2) * NCHUNK_ + col];
        float v3 = x[(size_t)(rb + 3) * NCHUNK_ + col];
        float v4 = x[(size_t)(rb + 4) * NCHUNK_ + col];
        float v5 = x[(size_t)(rb + 5) * NCHUNK_ + col];
        float v6 = x[(size_t)(rb + 6) * NCHUNK_ + col];
        float v7 = x[(size_t)(rb + 7) * NCHUNK_ + col];
        float4 pk;
        pk.x = h2f(__floats2half2_rn(v0, v1));
        pk.y = h2f(__floats2half2_rn(v2, v3));
        pk.z = h2f(__floats2half2_rn(v4, v5));
        pk.w = h2f(__floats2half2_rn(v6, v7));
        *reinterpret_cast<float4*>(&tile[col * 4]) = pk;
    }
    __syncthreads();

    // ---- gather: one class per thread, one-deep cm/w pipeline ----
    if (t < NCLASS_) {
        const int c = t;
        const float4* tile4 = reinterpret_cast<const float4*>(tile);

        const __half2 z_ = __floats2half2_rn(0.f, 0.f);
        __half2 a0 = z_, a1 = z_, a2 = z_, a3 = z_;
        float f0x = 0.f, f0y = 0.f, f1x = 0.f, f1y = 0.f;
        float f2x = 0.f, f2y = 0.f, f3x = 0.f, f3y = 0.f;

        // prime the pipeline with sg=0
        int4   ci;
        float4 wh;
        if constexpr (USET) {
            ci = cmT [c];
            wh = wTh4[c];
        } else {
            ci = reinterpret_cast<const int4*>(cmap + c * NSUPP_)[0];
            wh = reinterpret_cast<const float4*>(wSupp + c * NSUPP_)[0];
        }

        #pragma unroll
        for (int sg = 0; sg < SG_; ++sg) {
            const int4   c4 = ci;
            const float4 w4 = wh;

            // prefetch next group's cm/w (L2) past this group's math
            const int sgn = (sg + 1 < SG_) ? sg + 1 : SG_ - 1;
            if constexpr (USET) {
                ci = cmT [sgn * NCLASS_ + c];
                wh = wTh4[sgn * NCLASS_ + c];
            } else {
                ci = reinterpret_cast<const int4*>(cmap + c * NSUPP_)[sgn];
                wh = reinterpret_cast<const float4*>(wSupp + c * NSUPP_)[sgn];
            }

            // 4 independent ds_read_b128, then 16 v_pk_fma_f16
            const float4 d0 = tile4[c4.x];
            const float4 d1 = tile4[c4.y];
            const float4 d2 = tile4[c4.z];
            const float4 d3 = tile4[c4.w];

            const __half2 w0 = USET ? f2h2(w4.x) : __float2half2_rn(w4.x);
            const __half2 w1 = USET ? f2h2(w4.y) : __float2half2_rn(w4.y);
            const __half2 w2 = USET ? f2h2(w4.z) : __float2half2_rn(w4.z);
            const __half2 w3 = USET ? f2h2(w4.w) : __float2half2_rn(w4.w);

            GSUPP(d0, w0)
            GSUPP(d1, w1)
            GSUPP(d2, w2)
            GSUPP(d3, w3)

            // flush fp16 partials to f32 every 4 sg (16 supports):
            // bounds fp16 accumulation error to ~1% of feat
            if ((sg & 3) == 3) { FLUSH_ACC() }
        }

        out[(size_t)(rb + 0) * NCLASS_ + c] = __expf(f0x);
        out[(size_t)(rb + 1) * NCLASS_ + c] = __expf(f0y);
        out[(size_t)(rb + 2) * NCLASS_ + c] = __expf(f1x);
        out[(size_t)(rb + 3) * NCLASS_ + c] = __expf(f1y);
        out[(size_t)(rb + 4) * NCLASS_ + c] = __expf(f2x);
        out[(size_t)(rb + 5) * NCLASS_ + c] = __expf(f2y);
        out[(size_t)(rb + 6) * NCLASS_ + c] = __expf(f3x);
        out[(size_t)(rb + 7) * NCLASS_ + c] = __expf(f3y);
    }
}

extern "C" void kernel_launch(void* const* d_in, const int* in_sizes, int n_in,
                              void* d_out, int out_size, void* d_ws, size_t ws_size,
                              hipStream_t stream) {
    const float* x  = (const float*)d_in[0];   // (B, NCHUNK) fp32
    const float* w  = (const float*)d_in[1];   // (NCLASS, NSUPP) fp32
    const int*   cm = (const int*)d_in[2];     // (NCLASS, NSUPP) int32
    float*       o  = (float*)d_out;           // (B, NCLASS) fp32

    int*     cmT = (int*)d_ws;
    __half2* wTh = (__half2*)((char*)d_ws + CMT_BYTES);

    const dim3 grid(B_ / BT);                  // 512 blocks, 2 per CU
    if (ws_size >= WS_NEEDED) {
        build_cw_kernel<<<dim3((NCLASS_ + 3) / 4), dim3(256), 0, stream>>>(
            cm, w, cmT, wTh);
        supp_gather_kernel<true><<<grid, dim3(THREADS_), 0, stream>>>(
            x, w, cm, (const float4*)wTh, (const int4*)cmT, o);
    } else {
        supp_gather_kernel<false><<<grid, dim3(THREADS_), 0, stream>>>(
            x, w, cm, (const float4*)wTh, (const int4*)cmT, o);
    }
}